// Round 12
// baseline (254.171 us; speedup 1.0000x reference)
//
#include <hip/hip_runtime.h>

#define NN 100000
#define NE 1200000
#define DD 64
#define NTILES 3125        // NN/32 exact
#define NBK 391            // buckets, 256 rows each (row>>8); NBK*256 = 100096
#define MLEN (NBK * 256)   // count-matrix length
#define EPB 4688           // ceil(NE/256) edges per bucket-pass block

typedef unsigned int uint32;
typedef unsigned char uint8;
typedef unsigned short ushort16;
typedef __attribute__((ext_vector_type(8))) short short8;    // 8 bf16 (4 VGPR)
typedef __attribute__((ext_vector_type(16))) float f32x16;   // MFMA 32x32 acc

__device__ __forceinline__ ushort16 f2bf(float x) {
    uint32 u = __float_as_uint(x);
    u += 0x7FFFu + ((u >> 16) & 1u);   // round-to-nearest-even
    return (ushort16)(u >> 16);
}
__device__ __forceinline__ float bflo(uint32 u) { return __uint_as_float(u << 16); }
__device__ __forceinline__ float bfhi(uint32 u) { return __uint_as_float(u & 0xFFFF0000u); }
__device__ __forceinline__ uint32 pack2(float a, float b) {
    return (uint32)f2bf(a) | ((uint32)f2bf(b) << 16);
}

// ---- dual-stream gather: two independent edge->y chains per iteration ---
// halves the serial memory-latency depth per node; branchless odd-pad.
__device__ __forceinline__ void agg_edges(float& a0, float& a1, float& a2, float& a3,
                                          int s, int e, int fl,
                                          const uint32* __restrict__ edges,
                                          const uint2* __restrict__ y2) {
    int half = (e - s + 1) >> 1;
    int sB = s + half;
    #pragma unroll 4
    for (int i = 0; i < half; i++) {
        uint32 edA = edges[s + i];
        int jB = sB + i;
        uint32 edB = (jB < e) ? edges[jB] : 0u;   // pad: c=0, w=0 (harmless)
        int   cA = (int)(edA >> 15);
        float wA = (float)(edA & 32767u) * (1.0f / 32767.0f);
        int   cB = (int)(edB >> 15);
        float wB = (float)(edB & 32767u) * (1.0f / 32767.0f);
        uint2 yA = y2[cA * 16 + fl];
        uint2 yB = y2[cB * 16 + fl];
        a0 = fmaf(bflo(yA.x), wA, a0);
        a1 = fmaf(bfhi(yA.x), wA, a1);
        a2 = fmaf(bflo(yA.y), wA, a2);
        a3 = fmaf(bfhi(yA.y), wA, a3);
        a0 = fmaf(bflo(yB.x), wB, a0);
        a1 = fmaf(bfhi(yB.x), wB, a1);
        a2 = fmaf(bflo(yB.y), wB, a2);
        a3 = fmaf(bfhi(yB.y), wB, a3);
    }
}

// ---- Merged: bucket count (blocks 0..255) + W pre-pack (blocks 256..261) -

__global__ __launch_bounds__(512)
void k_init(const int* __restrict__ row, int* __restrict__ M,
            const float* __restrict__ selfk, const float* __restrict__ neighk,
            short8* __restrict__ wpack) {
    if (blockIdx.x >= 256) {
        int tid = (blockIdx.x - 256) * 512 + threadIdx.x;   // 0..3071
        if (tid < 3 * 16 * 64) {
            int lane  = tid & 63;
            int frag  = (tid >> 6) & 15;
            int layer = tid >> 10;
            int g = frag >> 3;
            int t = (frag >> 2) & 1;
            int s = frag & 3;
            const float* W = (g ? neighk : selfk) + layer * 4096;
            int n = t * 32 + (lane & 31);
            int k0 = s * 16 + (lane >> 5) * 8;
            short8 v;
            #pragma unroll
            for (int j = 0; j < 8; j++) v[j] = (short)f2bf(W[(k0 + j) * 64 + n]);
            wpack[tid] = v;
        }
        return;
    }
    __shared__ int bins[NBK];
    for (int i = threadIdx.x; i < NBK; i += 512) bins[i] = 0;
    __syncthreads();
    int start = blockIdx.x * EPB;
    int end = min(start + EPB, NE);
    for (int e = start + (int)threadIdx.x; e < end; e += 512)
        atomicAdd(&bins[row[e] >> 8], 1);
    __syncthreads();
    for (int i = threadIdx.x; i < NBK; i += 512)
        M[i * 256 + blockIdx.x] = bins[i];
}

// ---- CSR build (R8-proven) ----------------------------------------------

__global__ void k_scan1(const int* __restrict__ in, int* __restrict__ outx,
                        int* __restrict__ partials) {
    __shared__ int tmp[256];
    int t = threadIdx.x;
    int i = blockIdx.x * 256 + t;
    int v = (i < MLEN) ? in[i] : 0;
    tmp[t] = v;
    __syncthreads();
    #pragma unroll
    for (int off = 1; off < 256; off <<= 1) {
        int add = (t >= off) ? tmp[t - off] : 0;
        __syncthreads();
        tmp[t] += add;
        __syncthreads();
    }
    if (i < MLEN) outx[i] = tmp[t] - v;            // exclusive (within block)
    if (t == 255) partials[blockIdx.x] = tmp[255]; // block total
}

__global__ void k_scan2(int* __restrict__ partials) {
    __shared__ int tmp[512];
    int t = threadIdx.x;
    int v = (t < NBK) ? partials[t] : 0;
    tmp[t] = v;
    __syncthreads();
    #pragma unroll
    for (int off = 1; off < 512; off <<= 1) {
        int add = (t >= off) ? tmp[t - off] : 0;
        __syncthreads();
        tmp[t] += add;
        __syncthreads();
    }
    if (t < NBK) partials[t] = tmp[t] - v;         // exclusive
}

__global__ __launch_bounds__(512)
void k_bscatter(const int* __restrict__ row, const int* __restrict__ col,
                const float* __restrict__ ew, const int* __restrict__ Mscan,
                const int* __restrict__ partials,
                uint32* __restrict__ colw, uint8* __restrict__ rowlo) {
    __shared__ int cur[NBK];
    for (int i = threadIdx.x; i < NBK; i += 512)
        cur[i] = Mscan[i * 256 + blockIdx.x] + partials[i];
    __syncthreads();
    int start = blockIdx.x * EPB;
    int end = min(start + EPB, NE);
    for (int e = start + (int)threadIdx.x; e < end; e += 512) {
        int r = row[e];
        int wq = (int)(ew[e] * 32767.0f + 0.5f);
        wq = (wq > 32767) ? 32767 : wq;
        int p = atomicAdd(&cur[r >> 8], 1);
        colw[p]  = ((uint32)col[e] << 15) | (uint32)wq;
        rowlo[p] = (uint8)(r & 255);
    }
}

__global__ __launch_bounds__(256)
void k_build(const int* __restrict__ Mscan, const int* __restrict__ partials,
             const uint32* __restrict__ colw, const uint8* __restrict__ rowlo,
             uint32* __restrict__ edges, int* __restrict__ offsets) {
    __shared__ int bins[256];
    __shared__ int tmp[256];
    __shared__ int cur[256];
    int b = blockIdx.x;
    int t = threadIdx.x;
    int bstart = Mscan[b * 256] + partials[b];
    int bend   = (b == NBK - 1) ? NE : Mscan[(b + 1) * 256] + partials[b + 1];
    bins[t] = 0;
    __syncthreads();
    for (int p = bstart + t; p < bend; p += 256)
        atomicAdd(&bins[rowlo[p]], 1);
    __syncthreads();
    int v = bins[t];
    tmp[t] = v;
    __syncthreads();
    #pragma unroll
    for (int off = 1; off < 256; off <<= 1) {
        int add = (t >= off) ? tmp[t - off] : 0;
        __syncthreads();
        tmp[t] += add;
        __syncthreads();
    }
    int base = bstart + (tmp[t] - v);
    cur[t] = base;
    int rowid = b * 256 + t;
    if (rowid < NN) offsets[rowid] = base;
    if (b == 0 && t == 0) offsets[NN] = NE;
    __syncthreads();
    for (int p = bstart + t; p < bend; p += 256) {
        uint32 cw = colw[p];
        int dst = atomicAdd(&cur[rowlo[p]], 1);
        edges[dst] = cw;                 // block-private range: full lines
    }
}

// ---- MFMA GEMM (layer 1 only): hs = x@Ws + b, y = x@Wn ------------------

__global__ __launch_bounds__(256)
void gemm_mfma(const float* __restrict__ hf_, ushort16* __restrict__ hs,
               ushort16* __restrict__ y,
               const short8* __restrict__ wpack,
               const float* __restrict__ bias) {
    int lane  = threadIdx.x & 63;
    int wave  = threadIdx.x >> 6;
    int wid   = blockIdx.x * 4 + wave;
    int nwv   = gridDim.x * 4;
    int mrow  = lane & 31;
    int khalf = lane >> 5;
    int t     = wid & 1;

    short8 Wf[2][4];
    #pragma unroll
    for (int g = 0; g < 2; g++)
        #pragma unroll
        for (int s = 0; s < 4; s++)
            Wf[g][s] = wpack[(((g * 2 + t) * 4) + s) * 64 + lane];

    float bval = bias[t * 32 + mrow];

    for (int tile = wid >> 1; tile < NTILES; tile += nwv >> 1) {
        int n0 = tile * 32;
        const float* hf = hf_ + (n0 + mrow) * 64 + khalf * 8;
        short8 A[4];
        #pragma unroll
        for (int s = 0; s < 4; s++) {
            short8 a;
            #pragma unroll
            for (int j = 0; j < 8; j++) a[j] = (short)f2bf(hf[s * 16 + j]);
            A[s] = a;
        }

        f32x16 acc0, acc1;
        #pragma unroll
        for (int r = 0; r < 16; r++) { acc0[r] = 0.f; acc1[r] = 0.f; }

        #pragma unroll
        for (int s = 0; s < 4; s++) {
            acc0 = __builtin_amdgcn_mfma_f32_32x32x16_bf16(A[s], Wf[0][s], acc0, 0, 0, 0);
            acc1 = __builtin_amdgcn_mfma_f32_32x32x16_bf16(A[s], Wf[1][s], acc1, 0, 0, 0);
        }

        int colbase = t * 32 + mrow;
        #pragma unroll
        for (int r = 0; r < 16; r++) {
            int rw = (r & 3) + 8 * (r >> 2) + 4 * khalf;
            int n = n0 + rw;
            hs[n * DD + colbase] = f2bf(acc0[r] + bval);
            y [n * DD + colbase] = f2bf(acc1[r]);
        }
    }
}

// ---- Fused agg + next-layer GEMM ---------------------------------------
// Block = 32 nodes. Agg phase: 4 waves x 8 nodes (16-lane group per node,
// dual-stream gather). h packed bf16 into LDS (stride 36 uints = 144 B).
// Gemm phase: wave = gsel*2 + t, 4 MFMA.

__global__ __launch_bounds__(256)
void agg_gemm(const uint2* __restrict__ hs2, const uint2* __restrict__ y2,
              ushort16* __restrict__ hs_out, ushort16* __restrict__ y_out,
              const int* __restrict__ offsets, const uint32* __restrict__ edges,
              const short8* __restrict__ wpack, const float* __restrict__ bias) {
    __shared__ uint32 sh[32 * 36];
    int lane = threadIdx.x & 63;
    int wave = threadIdx.x >> 6;
    int g  = lane >> 4;          // group 0..3
    int fl = lane & 15;          // feature quad
    int n0 = blockIdx.x * 32;

    #pragma unroll
    for (int q = 0; q < 2; q++) {
        int lrow = wave * 8 + q * 4 + g;     // 0..31
        int n = n0 + lrow;
        uint2 hv = hs2[n * 16 + fl];
        float a0 = bflo(hv.x), a1 = bfhi(hv.x), a2 = bflo(hv.y), a3 = bfhi(hv.y);
        agg_edges(a0, a1, a2, a3, offsets[n], offsets[n + 1], fl, edges, y2);
        sh[lrow * 36 + fl * 2]     = pack2(fmaxf(a0, 0.f), fmaxf(a1, 0.f));
        sh[lrow * 36 + fl * 2 + 1] = pack2(fmaxf(a2, 0.f), fmaxf(a3, 0.f));
    }
    __syncthreads();

    // gemm phase
    int mrow  = lane & 31;
    int khalf = lane >> 5;
    int gsel  = wave >> 1;       // 0=self(hs) 1=neigh(y)
    int t     = wave & 1;        // col half

    short8 Wf[4];
    #pragma unroll
    for (int s = 0; s < 4; s++)
        Wf[s] = wpack[(((gsel * 2 + t) * 4) + s) * 64 + lane];

    short8 A[4];
    #pragma unroll
    for (int s = 0; s < 4; s++)
        A[s] = *(const short8*)&sh[mrow * 36 + s * 8 + khalf * 4];   // 16B, aligned

    f32x16 acc;
    #pragma unroll
    for (int r = 0; r < 16; r++) acc[r] = 0.f;
    #pragma unroll
    for (int s = 0; s < 4; s++)
        acc = __builtin_amdgcn_mfma_f32_32x32x16_bf16(A[s], Wf[s], acc, 0, 0, 0);

    float bval = gsel ? 0.f : bias[t * 32 + mrow];
    ushort16* dst = gsel ? y_out : hs_out;
    int colbase = t * 32 + mrow;
    #pragma unroll
    for (int r = 0; r < 16; r++) {
        int rw = (r & 3) + 8 * (r >> 2) + 4 * khalf;
        int n = n0 + rw;
        dst[n * DD + colbase] = f2bf(acc[r] + bval);
    }
}

// ---- Final aggregate: out = relu(hs[n] + sum_j w_j * y[col_j]), f32 ----

__global__ __launch_bounds__(256)
void agg_final(const uint2* __restrict__ hs2, const uint2* __restrict__ y2,
               float4* __restrict__ out, const int* __restrict__ offsets,
               const uint32* __restrict__ edges) {
    int lane = threadIdx.x & 63;
    int wave = threadIdx.x >> 6;
    int g  = lane >> 4;
    int fl = lane & 15;
    int n = (blockIdx.x * 4 + wave) * 4 + g;   // 6250*16 == NN exact

    uint2 hv = hs2[n * 16 + fl];
    float a0 = bflo(hv.x), a1 = bfhi(hv.x), a2 = bflo(hv.y), a3 = bfhi(hv.y);
    agg_edges(a0, a1, a2, a3, offsets[n], offsets[n + 1], fl, edges, y2);
    out[n * 16 + fl] = make_float4(fmaxf(a0, 0.f), fmaxf(a1, 0.f),
                                   fmaxf(a2, 0.f), fmaxf(a3, 0.f));
}

// ---- launch -------------------------------------------------------------

extern "C" void kernel_launch(void* const* d_in, const int* in_sizes, int n_in,
                              void* d_out, int out_size, void* d_ws, size_t ws_size,
                              hipStream_t stream) {
    const float* x      = (const float*)d_in[0];
    const int*   ei     = (const int*)d_in[1];
    const float* ew     = (const float*)d_in[2];
    const float* selfk  = (const float*)d_in[3];
    const float* neighk = (const float*)d_in[4];
    const float* biases = (const float*)d_in[5];
    float* out = (float*)d_out;

    char* w = (char*)d_ws;
    ushort16* hsA   = (ushort16*)w; w += (size_t)NN * DD * sizeof(ushort16);
    ushort16* yA    = (ushort16*)w; w += (size_t)NN * DD * sizeof(ushort16);
    ushort16* hsB   = (ushort16*)w; w += (size_t)NN * DD * sizeof(ushort16);
    ushort16* yB    = (ushort16*)w; w += (size_t)NN * DD * sizeof(ushort16);
    uint32* edges   = (uint32*)w;   w += (size_t)NE * sizeof(uint32);
    uint32* colwB   = (uint32*)w;   w += (size_t)NE * sizeof(uint32);
    uint8*  rowlo   = (uint8*)w;    w += (size_t)NE * sizeof(uint8);
    w = (char*)(((size_t)w + 255) & ~(size_t)255);
    int*    M       = (int*)w;      w += (size_t)MLEN * sizeof(int);
    int*    Mscan   = (int*)w;      w += (size_t)MLEN * sizeof(int);
    int*    offsets = (int*)w;      w += (size_t)(NN + 1) * sizeof(int);
    int*    partials= (int*)w;      w += 512 * sizeof(int);
    short8* wpack   = (short8*)w;   w += (size_t)3 * 16 * 64 * sizeof(short8);

    const int* row = ei;
    const int* col = ei + NE;

    k_init    <<<262, 512, 0, stream>>>(row, M, selfk, neighk, wpack);
    k_scan1   <<<NBK, 256, 0, stream>>>(M, Mscan, partials);
    k_scan2   <<<1, 512, 0, stream>>>(partials);
    k_bscatter<<<256, 512, 0, stream>>>(row, col, ew, Mscan, partials, colwB, rowlo);
    k_build   <<<NBK, 256, 0, stream>>>(Mscan, partials, colwB, rowlo, edges, offsets);

    // layer 1 GEMM: x (f32) -> hsA, yA
    gemm_mfma<<<782, 256, 0, stream>>>(x, hsA, yA, wpack, biases);
    // agg(layer1) + GEMM(layer2): -> hsB, yB
    agg_gemm <<<NTILES, 256, 0, stream>>>((const uint2*)hsA, (const uint2*)yA,
                                          hsB, yB, offsets, edges,
                                          wpack + 1024, biases + 64);
    // agg(layer2) + GEMM(layer3): -> hsA, yA
    agg_gemm <<<NTILES, 256, 0, stream>>>((const uint2*)hsB, (const uint2*)yB,
                                          hsA, yA, offsets, edges,
                                          wpack + 2048, biases + 128);
    // final aggregate -> out (f32)
    agg_final<<<NN / 16, 256, 0, stream>>>((const uint2*)hsA, (const uint2*)yA,
                                           (float4*)out, offsets, edges);
}

// Round 13
// 227.792 us; speedup vs baseline: 1.1158x; 1.1158x over previous
//
#include <hip/hip_runtime.h>

#define NN 100000
#define NE 1200000
#define DD 64
#define NTILES 3125        // NN/32 exact
#define NBK 391            // buckets, 256 rows each (row>>8); NBK*256 = 100096
#define MLEN (NBK * 256)   // count-matrix length
#define EPB 4688           // ceil(NE/256) edges per bucket-pass block

typedef unsigned int uint32;
typedef unsigned char uint8;
typedef unsigned short ushort16;
typedef __attribute__((ext_vector_type(8))) short short8;    // 8 bf16 (4 VGPR)
typedef __attribute__((ext_vector_type(16))) float f32x16;   // MFMA 32x32 acc

__device__ __forceinline__ ushort16 f2bf(float x) {
    uint32 u = __float_as_uint(x);
    u += 0x7FFFu + ((u >> 16) & 1u);   // round-to-nearest-even
    return (ushort16)(u >> 16);
}
__device__ __forceinline__ float bflo(uint32 u) { return __uint_as_float(u << 16); }
__device__ __forceinline__ float bfhi(uint32 u) { return __uint_as_float(u & 0xFFFF0000u); }
__device__ __forceinline__ uint32 pack2(float a, float b) {
    return (uint32)f2bf(a) | ((uint32)f2bf(b) << 16);
}

// ---- gather loop: 8-lane group per node, lane owns 8 feats (uint4). -----
// One wave gather instruction = 8 nodes' rows = 8 edges. Plain R8-style
// loop (ILP variants R10-R12 all regressed: issue-throughput bound).
__device__ __forceinline__ void agg_edges8(float* a, int s, int e, int fl,
                                           const uint32* __restrict__ edges,
                                           const uint4* __restrict__ y4) {
    #pragma unroll 4
    for (int j = s; j < e; j++) {
        uint32 ed = edges[j];
        int c = (int)(ed >> 15);
        float w = (float)(ed & 32767u) * (1.0f / 32767.0f);
        uint4 yv = y4[c * 8 + fl];
        a[0] = fmaf(bflo(yv.x), w, a[0]);
        a[1] = fmaf(bfhi(yv.x), w, a[1]);
        a[2] = fmaf(bflo(yv.y), w, a[2]);
        a[3] = fmaf(bfhi(yv.y), w, a[3]);
        a[4] = fmaf(bflo(yv.z), w, a[4]);
        a[5] = fmaf(bfhi(yv.z), w, a[5]);
        a[6] = fmaf(bflo(yv.w), w, a[6]);
        a[7] = fmaf(bfhi(yv.w), w, a[7]);
    }
}

// ---- Merged: bucket count (blocks 0..255) + W pre-pack (blocks 256..261) -

__global__ __launch_bounds__(512)
void k_init(const int* __restrict__ row, int* __restrict__ M,
            const float* __restrict__ selfk, const float* __restrict__ neighk,
            short8* __restrict__ wpack) {
    if (blockIdx.x >= 256) {
        int tid = (blockIdx.x - 256) * 512 + threadIdx.x;   // 0..3071
        if (tid < 3 * 16 * 64) {
            int lane  = tid & 63;
            int frag  = (tid >> 6) & 15;
            int layer = tid >> 10;
            int g = frag >> 3;
            int t = (frag >> 2) & 1;
            int s = frag & 3;
            const float* W = (g ? neighk : selfk) + layer * 4096;
            int n = t * 32 + (lane & 31);
            int k0 = s * 16 + (lane >> 5) * 8;
            short8 v;
            #pragma unroll
            for (int j = 0; j < 8; j++) v[j] = (short)f2bf(W[(k0 + j) * 64 + n]);
            wpack[tid] = v;
        }
        return;
    }
    __shared__ int bins[NBK];
    for (int i = threadIdx.x; i < NBK; i += 512) bins[i] = 0;
    __syncthreads();
    int start = blockIdx.x * EPB;
    int end = min(start + EPB, NE);
    for (int e = start + (int)threadIdx.x; e < end; e += 512)
        atomicAdd(&bins[row[e] >> 8], 1);
    __syncthreads();
    for (int i = threadIdx.x; i < NBK; i += 512)
        M[i * 256 + blockIdx.x] = bins[i];
}

// ---- CSR build (R8-proven) ----------------------------------------------

__global__ void k_scan1(const int* __restrict__ in, int* __restrict__ outx,
                        int* __restrict__ partials) {
    __shared__ int tmp[256];
    int t = threadIdx.x;
    int i = blockIdx.x * 256 + t;
    int v = (i < MLEN) ? in[i] : 0;
    tmp[t] = v;
    __syncthreads();
    #pragma unroll
    for (int off = 1; off < 256; off <<= 1) {
        int add = (t >= off) ? tmp[t - off] : 0;
        __syncthreads();
        tmp[t] += add;
        __syncthreads();
    }
    if (i < MLEN) outx[i] = tmp[t] - v;            // exclusive (within block)
    if (t == 255) partials[blockIdx.x] = tmp[255]; // block total
}

__global__ void k_scan2(int* __restrict__ partials) {
    __shared__ int tmp[512];
    int t = threadIdx.x;
    int v = (t < NBK) ? partials[t] : 0;
    tmp[t] = v;
    __syncthreads();
    #pragma unroll
    for (int off = 1; off < 512; off <<= 1) {
        int add = (t >= off) ? tmp[t - off] : 0;
        __syncthreads();
        tmp[t] += add;
        __syncthreads();
    }
    if (t < NBK) partials[t] = tmp[t] - v;         // exclusive
}

__global__ __launch_bounds__(512)
void k_bscatter(const int* __restrict__ row, const int* __restrict__ col,
                const float* __restrict__ ew, const int* __restrict__ Mscan,
                const int* __restrict__ partials,
                uint32* __restrict__ colw, uint8* __restrict__ rowlo) {
    __shared__ int cur[NBK];
    for (int i = threadIdx.x; i < NBK; i += 512)
        cur[i] = Mscan[i * 256 + blockIdx.x] + partials[i];
    __syncthreads();
    int start = blockIdx.x * EPB;
    int end = min(start + EPB, NE);
    for (int e = start + (int)threadIdx.x; e < end; e += 512) {
        int r = row[e];
        int wq = (int)(ew[e] * 32767.0f + 0.5f);
        wq = (wq > 32767) ? 32767 : wq;
        int p = atomicAdd(&cur[r >> 8], 1);
        colw[p]  = ((uint32)col[e] << 15) | (uint32)wq;
        rowlo[p] = (uint8)(r & 255);
    }
}

__global__ __launch_bounds__(256)
void k_build(const int* __restrict__ Mscan, const int* __restrict__ partials,
             const uint32* __restrict__ colw, const uint8* __restrict__ rowlo,
             uint32* __restrict__ edges, int* __restrict__ offsets) {
    __shared__ int bins[256];
    __shared__ int tmp[256];
    __shared__ int cur[256];
    int b = blockIdx.x;
    int t = threadIdx.x;
    int bstart = Mscan[b * 256] + partials[b];
    int bend   = (b == NBK - 1) ? NE : Mscan[(b + 1) * 256] + partials[b + 1];
    bins[t] = 0;
    __syncthreads();
    for (int p = bstart + t; p < bend; p += 256)
        atomicAdd(&bins[rowlo[p]], 1);
    __syncthreads();
    int v = bins[t];
    tmp[t] = v;
    __syncthreads();
    #pragma unroll
    for (int off = 1; off < 256; off <<= 1) {
        int add = (t >= off) ? tmp[t - off] : 0;
        __syncthreads();
        tmp[t] += add;
        __syncthreads();
    }
    int base = bstart + (tmp[t] - v);
    cur[t] = base;
    int rowid = b * 256 + t;
    if (rowid < NN) offsets[rowid] = base;
    if (b == 0 && t == 0) offsets[NN] = NE;
    __syncthreads();
    for (int p = bstart + t; p < bend; p += 256) {
        uint32 cw = colw[p];
        int dst = atomicAdd(&cur[rowlo[p]], 1);
        edges[dst] = cw;                 // block-private range: full lines
    }
}

// ---- MFMA GEMM (layer 1 only): hs = x@Ws + b, y = x@Wn ------------------

__global__ __launch_bounds__(256)
void gemm_mfma(const float* __restrict__ hf_, ushort16* __restrict__ hs,
               ushort16* __restrict__ y,
               const short8* __restrict__ wpack,
               const float* __restrict__ bias) {
    int lane  = threadIdx.x & 63;
    int wave  = threadIdx.x >> 6;
    int wid   = blockIdx.x * 4 + wave;
    int nwv   = gridDim.x * 4;
    int mrow  = lane & 31;
    int khalf = lane >> 5;
    int t     = wid & 1;

    short8 Wf[2][4];
    #pragma unroll
    for (int g = 0; g < 2; g++)
        #pragma unroll
        for (int s = 0; s < 4; s++)
            Wf[g][s] = wpack[(((g * 2 + t) * 4) + s) * 64 + lane];

    float bval = bias[t * 32 + mrow];

    for (int tile = wid >> 1; tile < NTILES; tile += nwv >> 1) {
        int n0 = tile * 32;
        const float* hf = hf_ + (n0 + mrow) * 64 + khalf * 8;
        short8 A[4];
        #pragma unroll
        for (int s = 0; s < 4; s++) {
            short8 a;
            #pragma unroll
            for (int j = 0; j < 8; j++) a[j] = (short)f2bf(hf[s * 16 + j]);
            A[s] = a;
        }

        f32x16 acc0, acc1;
        #pragma unroll
        for (int r = 0; r < 16; r++) { acc0[r] = 0.f; acc1[r] = 0.f; }

        #pragma unroll
        for (int s = 0; s < 4; s++) {
            acc0 = __builtin_amdgcn_mfma_f32_32x32x16_bf16(A[s], Wf[0][s], acc0, 0, 0, 0);
            acc1 = __builtin_amdgcn_mfma_f32_32x32x16_bf16(A[s], Wf[1][s], acc1, 0, 0, 0);
        }

        int colbase = t * 32 + mrow;
        #pragma unroll
        for (int r = 0; r < 16; r++) {
            int rw = (r & 3) + 8 * (r >> 2) + 4 * khalf;
            int n = n0 + rw;
            hs[n * DD + colbase] = f2bf(acc0[r] + bval);
            y [n * DD + colbase] = f2bf(acc1[r]);
        }
    }
}

// ---- Fused agg + next-layer GEMM ---------------------------------------
// Block = 32 nodes = 4 waves x 8 nodes (8-lane group per node, lane owns
// 8 feats via uint4). One gather instr = 8 edges. h packed bf16 into LDS
// (stride 36 uints = 144 B). Gemm phase: wave = gsel*2 + t, 4 MFMA.

__global__ __launch_bounds__(256)
void agg_gemm(const uint4* __restrict__ hs4, const uint4* __restrict__ y4,
              ushort16* __restrict__ hs_out, ushort16* __restrict__ y_out,
              const int* __restrict__ offsets, const uint32* __restrict__ edges,
              const short8* __restrict__ wpack, const float* __restrict__ bias) {
    __shared__ uint32 sh[32 * 36];
    int lane = threadIdx.x & 63;
    int wave = threadIdx.x >> 6;
    int g  = lane >> 3;          // group 0..7 -> node
    int fl = lane & 7;           // feature octet
    int n0 = blockIdx.x * 32;
    int lrow = wave * 8 + g;     // 0..31
    int n = n0 + lrow;

    uint4 hv = hs4[n * 8 + fl];
    float a[8] = {bflo(hv.x), bfhi(hv.x), bflo(hv.y), bfhi(hv.y),
                  bflo(hv.z), bfhi(hv.z), bflo(hv.w), bfhi(hv.w)};
    agg_edges8(a, offsets[n], offsets[n + 1], fl, edges, y4);

    uint32* dstp = &sh[lrow * 36 + fl * 4];
    dstp[0] = pack2(fmaxf(a[0], 0.f), fmaxf(a[1], 0.f));
    dstp[1] = pack2(fmaxf(a[2], 0.f), fmaxf(a[3], 0.f));
    dstp[2] = pack2(fmaxf(a[4], 0.f), fmaxf(a[5], 0.f));
    dstp[3] = pack2(fmaxf(a[6], 0.f), fmaxf(a[7], 0.f));
    __syncthreads();

    // gemm phase
    int mrow  = lane & 31;
    int khalf = lane >> 5;
    int gsel  = wave >> 1;       // 0=self(hs) 1=neigh(y)
    int t     = wave & 1;        // col half

    short8 Wf[4];
    #pragma unroll
    for (int s = 0; s < 4; s++)
        Wf[s] = wpack[(((gsel * 2 + t) * 4) + s) * 64 + lane];

    short8 A[4];
    #pragma unroll
    for (int s = 0; s < 4; s++)
        A[s] = *(const short8*)&sh[mrow * 36 + s * 8 + khalf * 4];   // 16B, aligned

    f32x16 acc;
    #pragma unroll
    for (int r = 0; r < 16; r++) acc[r] = 0.f;
    #pragma unroll
    for (int s = 0; s < 4; s++)
        acc = __builtin_amdgcn_mfma_f32_32x32x16_bf16(A[s], Wf[s], acc, 0, 0, 0);

    float bval = gsel ? 0.f : bias[t * 32 + mrow];
    ushort16* dst = gsel ? y_out : hs_out;
    int colbase = t * 32 + mrow;
    #pragma unroll
    for (int r = 0; r < 16; r++) {
        int rw = (r & 3) + 8 * (r >> 2) + 4 * khalf;
        int nn = n0 + rw;
        dst[nn * DD + colbase] = f2bf(acc[r] + bval);
    }
}

// ---- Final aggregate: out = relu(hs[n] + sum_j w_j * y[col_j]), f32 ----

__global__ __launch_bounds__(256)
void agg_final(const uint4* __restrict__ hs4, const uint4* __restrict__ y4,
               float4* __restrict__ out, const int* __restrict__ offsets,
               const uint32* __restrict__ edges) {
    int lane = threadIdx.x & 63;
    int wave = threadIdx.x >> 6;
    int g  = lane >> 3;          // group 0..7 -> node
    int fl = lane & 7;           // feature octet
    int n = blockIdx.x * 32 + wave * 8 + g;   // 3125*32 == NN exact

    uint4 hv = hs4[n * 8 + fl];
    float a[8] = {bflo(hv.x), bfhi(hv.x), bflo(hv.y), bfhi(hv.y),
                  bflo(hv.z), bfhi(hv.z), bflo(hv.w), bfhi(hv.w)};
    agg_edges8(a, offsets[n], offsets[n + 1], fl, edges, y4);

    out[n * 16 + fl * 2]     = make_float4(fmaxf(a[0], 0.f), fmaxf(a[1], 0.f),
                                           fmaxf(a[2], 0.f), fmaxf(a[3], 0.f));
    out[n * 16 + fl * 2 + 1] = make_float4(fmaxf(a[4], 0.f), fmaxf(a[5], 0.f),
                                           fmaxf(a[6], 0.f), fmaxf(a[7], 0.f));
}

// ---- launch -------------------------------------------------------------

extern "C" void kernel_launch(void* const* d_in, const int* in_sizes, int n_in,
                              void* d_out, int out_size, void* d_ws, size_t ws_size,
                              hipStream_t stream) {
    const float* x      = (const float*)d_in[0];
    const int*   ei     = (const int*)d_in[1];
    const float* ew     = (const float*)d_in[2];
    const float* selfk  = (const float*)d_in[3];
    const float* neighk = (const float*)d_in[4];
    const float* biases = (const float*)d_in[5];
    float* out = (float*)d_out;

    char* w = (char*)d_ws;
    ushort16* hsA   = (ushort16*)w; w += (size_t)NN * DD * sizeof(ushort16);
    ushort16* yA    = (ushort16*)w; w += (size_t)NN * DD * sizeof(ushort16);
    ushort16* hsB   = (ushort16*)w; w += (size_t)NN * DD * sizeof(ushort16);
    ushort16* yB    = (ushort16*)w; w += (size_t)NN * DD * sizeof(ushort16);
    uint32* edges   = (uint32*)w;   w += (size_t)NE * sizeof(uint32);
    uint32* colwB   = (uint32*)w;   w += (size_t)NE * sizeof(uint32);
    uint8*  rowlo   = (uint8*)w;    w += (size_t)NE * sizeof(uint8);
    w = (char*)(((size_t)w + 255) & ~(size_t)255);
    int*    M       = (int*)w;      w += (size_t)MLEN * sizeof(int);
    int*    Mscan   = (int*)w;      w += (size_t)MLEN * sizeof(int);
    int*    offsets = (int*)w;      w += (size_t)(NN + 1) * sizeof(int);
    int*    partials= (int*)w;      w += 512 * sizeof(int);
    short8* wpack   = (short8*)w;   w += (size_t)3 * 16 * 64 * sizeof(short8);

    const int* row = ei;
    const int* col = ei + NE;

    k_init    <<<262, 512, 0, stream>>>(row, M, selfk, neighk, wpack);
    k_scan1   <<<NBK, 256, 0, stream>>>(M, Mscan, partials);
    k_scan2   <<<1, 512, 0, stream>>>(partials);
    k_bscatter<<<256, 512, 0, stream>>>(row, col, ew, Mscan, partials, colwB, rowlo);
    k_build   <<<NBK, 256, 0, stream>>>(Mscan, partials, colwB, rowlo, edges, offsets);

    // layer 1 GEMM: x (f32) -> hsA, yA
    gemm_mfma<<<782, 256, 0, stream>>>(x, hsA, yA, wpack, biases);
    // agg(layer1) + GEMM(layer2): -> hsB, yB
    agg_gemm <<<NTILES, 256, 0, stream>>>((const uint4*)hsA, (const uint4*)yA,
                                          hsB, yB, offsets, edges,
                                          wpack + 1024, biases + 64);
    // agg(layer2) + GEMM(layer3): -> hsA, yA
    agg_gemm <<<NTILES, 256, 0, stream>>>((const uint4*)hsB, (const uint4*)yB,
                                          hsA, yA, offsets, edges,
                                          wpack + 2048, biases + 128);
    // final aggregate -> out (f32)
    agg_final<<<NTILES, 256, 0, stream>>>((const uint4*)hsA, (const uint4*)yA,
                                          (float4*)out, offsets, edges);
}